// Round 16
// baseline (95.922 us; speedup 1.0000x reference)
//
#include <hip/hip_runtime.h>
#include <stdint.h>

#define UNITS  4096
#define SEG    64         // per-wave segment; per-wave window count 44.1 +- 6.5 -> +3.1 sigma
#define NSLOT  4          // slots per lane = segments; slot i offset = lane
#define LOF    0.4625f    // theta ~= 0.5244 +- 0.0206 ; [LO,HI) ~= +-3 sigma
#define HIF    0.5865f
#define SELBITS 22        // bits(HIF)-bits(LOF) = 0x295810 < 2^22

typedef float v4f __attribute__((ext_vector_type(4)));

// LDS-only barrier (no vmcnt drain -> loads/stores stay in flight)
__device__ __forceinline__ void lds_barrier() {
    asm volatile("s_waitcnt lgkmcnt(0)" ::: "memory");
    __builtin_amdgcn_s_barrier();
}
__device__ __forceinline__ uint32_t flipu(uint32_t b) {
    return b ^ (uint32_t)(((int32_t)b >> 31) | (int32_t)0x80000000);
}
__device__ __forceinline__ uint32_t mbcnt64(uint64_t m) {
    return __builtin_amdgcn_mbcnt_hi((uint32_t)(m >> 32),
           __builtin_amdgcn_mbcnt_lo((uint32_t)m, 0u));
}
// non-temporal 16B store (write-once output: don't pollute L2/L3)
__device__ __forceinline__ void nt_store4(float* p, float a, float b, float c, float d) {
    v4f v = {a, b, c, d};
    __builtin_nontemporal_store(v, (v4f*)p);
}

// One block (256 threads) = TWO rows, both register-resident.
// All 32 dwordx4 loads issue up front; fused window pass per row into
// per-wave LDS segments (no atomics); ONE barrier for both rows; two
// independent 4-wave-redundant unrolled 11-round 2-bit ballot selects;
// nt mask-stores from registers. Bracket + segment overflow verified per
// row; misses take the exact block-wide 32-bit bit-search fallback.
__global__ __launch_bounds__(256, 8) void ksparse_select_kernel(
        const float* __restrict__ X, float* __restrict__ out, int kidx, int nrows) {
    __shared__ uint32_t listA[4 * SEG];  // 1 KiB
    __shared__ uint32_t listB[4 * SEG];  // 1 KiB
    __shared__ uint32_t wnbA[4], wcA[4];
    __shared__ uint32_t wnbB[4], wcB[4];
    __shared__ uint32_t fbc[4];

    const int t    = threadIdx.x;
    const int w    = t >> 6;
    const int lane = t & 63;

    const int rowA = (int)blockIdx.x * 2;
    const int rowB = rowA + 1;
    const bool hasB = rowB < nrows;                 // block-uniform
    const int rowBs = hasB ? rowB : rowA;           // safe address

    // issue ALL loads up front (independent register targets)
    float fA[16], fB[16];
    {
        const float4* Xa = reinterpret_cast<const float4*>(X + (size_t)rowA  * UNITS);
        const float4* Xb = reinterpret_cast<const float4*>(X + (size_t)rowBs * UNITS);
#pragma unroll
        for (int j = 0; j < 4; ++j) {
            float4 v = Xa[j * 256 + t];
            fA[4*j] = v.x; fA[4*j+1] = v.y; fA[4*j+2] = v.z; fA[4*j+3] = v.w;
        }
#pragma unroll
        for (int j = 0; j < 4; ++j) {
            float4 v = Xb[j * 256 + t];
            fB[4*j] = v.x; fB[4*j+1] = v.y; fB[4*j+2] = v.z; fB[4*j+3] = v.w;
        }
    }

    const uint32_t k   = (uint32_t)kidx;
    const uint32_t LOu = __float_as_uint(LOF);

    // ---- pass 1A: fused count + per-wave-segment scatter (row A)
    {
        uint32_t nbw = 0, pfx = 0;
#pragma unroll
        for (int e = 0; e < 16; ++e) {
            const bool lo = fA[e] < LOF;
            const bool hi = fA[e] < HIF;
            const uint64_t mlo  = __ballot(lo);
            const uint64_t mwin = __ballot(hi && !lo);
            nbw += (uint32_t)__popcll(mlo);
            if (hi && !lo) {
                const uint32_t off = pfx + mbcnt64(mwin);
                if (off < SEG) listA[SEG * w + off] = __float_as_uint(fA[e]) - LOu;
            }
            pfx += (uint32_t)__popcll(mwin);
        }
        if (lane == 0) { wnbA[w] = nbw; wcA[w] = pfx; }
    }
    // ---- pass 1B: row B
    {
        uint32_t nbw = 0, pfx = 0;
#pragma unroll
        for (int e = 0; e < 16; ++e) {
            const bool lo = fB[e] < LOF;
            const bool hi = fB[e] < HIF;
            const uint64_t mlo  = __ballot(lo);
            const uint64_t mwin = __ballot(hi && !lo);
            nbw += (uint32_t)__popcll(mlo);
            if (hi && !lo) {
                const uint32_t off = pfx + mbcnt64(mwin);
                if (off < SEG) listB[SEG * w + off] = __float_as_uint(fB[e]) - LOu;
            }
            pfx += (uint32_t)__popcll(mwin);
        }
        if (lane == 0) { wnbB[w] = nbw; wcB[w] = pfx; }
    }

    lds_barrier();  // both lists + counts visible (the ONLY fast-path barrier)

    const uint32_t a0 = wcA[0], a1 = wcA[1], a2 = wcA[2], a3 = wcA[3];
    const uint32_t cA  = a0 + a1 + a2 + a3;
    const uint32_t cbA = wnbA[0] + wnbA[1] + wnbA[2] + wnbA[3];
    const uint32_t mxA = max(max(a0, a1), max(a2, a3));
    const uint32_t b0 = wcB[0], b1 = wcB[1], b2 = wcB[2], b3 = wcB[3];
    const uint32_t cB  = b0 + b1 + b2 + b3;
    const uint32_t cbB = wnbB[0] + wnbB[1] + wnbB[2] + wnbB[3];
    const uint32_t mxB = max(max(b0, b1), max(b2, b3));

    const bool fastA = (cbA <= k) && (k < cbA + cA) && (mxA <= SEG);
    const bool fastB = hasB && (cbB <= k) && (k < cbB + cB) && (mxB <= SEG);

    float* Oa = out + (size_t)rowA  * UNITS;
    float* Obp = out + (size_t)rowBs * UNITS;

    if (fastA) {
        const uint32_t r = k - cbA;
        uint32_t sv[NSLOT];
        sv[0] = (lane < (int)a0) ? listA[0 * SEG + lane] : 0xFFFFFFFFu;
        sv[1] = (lane < (int)a1) ? listA[1 * SEG + lane] : 0xFFFFFFFFu;
        sv[2] = (lane < (int)a2) ? listA[2 * SEG + lane] : 0xFFFFFFFFu;
        sv[3] = (lane < (int)a3) ? listA[3 * SEG + lane] : 0xFFFFFFFFu;
        uint32_t p = 0;
#pragma unroll
        for (int rb = SELBITS - 2; rb >= 0; rb -= 2) {
            const uint32_t m1 = p | (1u << rb);
            const uint32_t m2 = p | (2u << rb);
            const uint32_t m3 = p | (3u << rb);
            uint32_t n1 = 0, n2 = 0, n3 = 0;
#pragma unroll
            for (int i = 0; i < NSLOT; ++i) {
                n1 += (uint32_t)__popcll(__ballot(sv[i] < m1));
                n2 += (uint32_t)__popcll(__ballot(sv[i] < m2));
                n3 += (uint32_t)__popcll(__ballot(sv[i] < m3));
            }
            if (n3 <= r)      p = m3;
            else if (n2 <= r) p = m2;
            else if (n1 <= r) p = m1;
        }
        const float th = __uint_as_float(LOu + p);
#pragma unroll
        for (int j = 0; j < 4; ++j) {
            nt_store4(Oa + 4 * (j * 256 + t),
                      (fA[4*j]   >= th) ? fA[4*j]   : 0.0f,
                      (fA[4*j+1] >= th) ? fA[4*j+1] : 0.0f,
                      (fA[4*j+2] >= th) ? fA[4*j+2] : 0.0f,
                      (fA[4*j+3] >= th) ? fA[4*j+3] : 0.0f);
        }
    }
    if (fastB) {
        const uint32_t r = k - cbB;
        uint32_t sv[NSLOT];
        sv[0] = (lane < (int)b0) ? listB[0 * SEG + lane] : 0xFFFFFFFFu;
        sv[1] = (lane < (int)b1) ? listB[1 * SEG + lane] : 0xFFFFFFFFu;
        sv[2] = (lane < (int)b2) ? listB[2 * SEG + lane] : 0xFFFFFFFFu;
        sv[3] = (lane < (int)b3) ? listB[3 * SEG + lane] : 0xFFFFFFFFu;
        uint32_t p = 0;
#pragma unroll
        for (int rb = SELBITS - 2; rb >= 0; rb -= 2) {
            const uint32_t m1 = p | (1u << rb);
            const uint32_t m2 = p | (2u << rb);
            const uint32_t m3 = p | (3u << rb);
            uint32_t n1 = 0, n2 = 0, n3 = 0;
#pragma unroll
            for (int i = 0; i < NSLOT; ++i) {
                n1 += (uint32_t)__popcll(__ballot(sv[i] < m1));
                n2 += (uint32_t)__popcll(__ballot(sv[i] < m2));
                n3 += (uint32_t)__popcll(__ballot(sv[i] < m3));
            }
            if (n3 <= r)      p = m3;
            else if (n2 <= r) p = m2;
            else if (n1 <= r) p = m1;
        }
        const float th = __uint_as_float(LOu + p);
#pragma unroll
        for (int j = 0; j < 4; ++j) {
            nt_store4(Obp + 4 * (j * 256 + t),
                      (fB[4*j]   >= th) ? fB[4*j]   : 0.0f,
                      (fB[4*j+1] >= th) ? fB[4*j+1] : 0.0f,
                      (fB[4*j+2] >= th) ? fB[4*j+2] : 0.0f,
                      (fB[4*j+3] >= th) ? fB[4*j+3] : 0.0f);
        }
    }

    if (!fastA) {   // exact block-wide fallback, row A (block-uniform entry)
        uint32_t p = 0;
#pragma unroll 1
        for (int b = 31; b >= 0; --b) {
            const uint32_t mid = p | (1u << b);
            uint32_t cw = 0;
#pragma unroll
            for (int e = 0; e < 16; ++e)
                cw += (uint32_t)__popcll(__ballot(flipu(__float_as_uint(fA[e])) < mid));
            if (lane == 0) fbc[w] = cw;
            lds_barrier();
            const uint32_t cm = fbc[0] + fbc[1] + fbc[2] + fbc[3];
            if (cm <= k) p = mid;
            lds_barrier();
        }
#pragma unroll
        for (int j = 0; j < 4; ++j) {
            nt_store4(Oa + 4 * (j * 256 + t),
                      (flipu(__float_as_uint(fA[4*j]))   >= p) ? fA[4*j]   : 0.0f,
                      (flipu(__float_as_uint(fA[4*j+1])) >= p) ? fA[4*j+1] : 0.0f,
                      (flipu(__float_as_uint(fA[4*j+2])) >= p) ? fA[4*j+2] : 0.0f,
                      (flipu(__float_as_uint(fA[4*j+3])) >= p) ? fA[4*j+3] : 0.0f);
        }
    }
    if (hasB && !fastB) {   // exact block-wide fallback, row B
        uint32_t p = 0;
#pragma unroll 1
        for (int b = 31; b >= 0; --b) {
            const uint32_t mid = p | (1u << b);
            uint32_t cw = 0;
#pragma unroll
            for (int e = 0; e < 16; ++e)
                cw += (uint32_t)__popcll(__ballot(flipu(__float_as_uint(fB[e])) < mid));
            if (lane == 0) fbc[w] = cw;
            lds_barrier();
            const uint32_t cm = fbc[0] + fbc[1] + fbc[2] + fbc[3];
            if (cm <= k) p = mid;
            lds_barrier();
        }
#pragma unroll
        for (int j = 0; j < 4; ++j) {
            nt_store4(Obp + 4 * (j * 256 + t),
                      (flipu(__float_as_uint(fB[4*j]))   >= p) ? fB[4*j]   : 0.0f,
                      (flipu(__float_as_uint(fB[4*j+1])) >= p) ? fB[4*j+1] : 0.0f,
                      (flipu(__float_as_uint(fB[4*j+2])) >= p) ? fB[4*j+2] : 0.0f,
                      (flipu(__float_as_uint(fB[4*j+3])) >= p) ? fB[4*j+3] : 0.0f);
        }
    }
}

extern "C" void kernel_launch(void* const* d_in, const int* in_sizes, int n_in,
                              void* d_out, int out_size, void* d_ws, size_t ws_size,
                              hipStream_t stream) {
    const float* X = (const float*)d_in[0];
    float* out = (float*)d_out;
    const int rows = in_sizes[0] / UNITS;
    const int kidx = (int)(0.7 * UNITS);  // 2867
    const int grid = (rows + 1) / 2;
    ksparse_select_kernel<<<grid, 256, 0, stream>>>(X, out, kidx, rows);
}